// Round 8
// baseline (1958.124 us; speedup 1.0000x reference)
//
#include <hip/hip_runtime.h>

#define NN 100000
#define NE 3200000
#define NG 256
#define H 32
#define CE 8                     // edges per thread chunk
#define NCH (NE / CE)            // 400000 chunks
#define SB ((NN + 255) / 256)    // 391 scan blocks

// Monotone bijection float -> u32 (order-preserving), so u32 max == float max.
__device__ __forceinline__ unsigned encf(float f) {
    unsigned u = __float_as_uint(f);
    return (u & 0x80000000u) ? ~u : (u | 0x80000000u);
}
__device__ __forceinline__ float decf(unsigned u) {
    return __uint_as_float((u & 0x80000000u) ? (u & 0x7fffffffu) : ~u);
}

// Flush a 32-wide register run-max to global agg (enc domain, test-before-atomic).
// agg starts at enc(0): values <=0 never pass the test (folds relu + neginf fill).
__device__ __forceinline__ void flush_row(unsigned* __restrict__ agg, int node,
                                          const float* m) {
    unsigned* ag = agg + (size_t)node * H;
#pragma unroll
    for (int r = 0; r < 8; r++) {
        uint4 c = ((const uint4*)ag)[r];
        unsigned v0 = encf(m[4 * r + 0]);
        unsigned v1 = encf(m[4 * r + 1]);
        unsigned v2 = encf(m[4 * r + 2]);
        unsigned v3 = encf(m[4 * r + 3]);
        if (v0 > c.x) atomicMax(ag + 4 * r + 0, v0);
        if (v1 > c.y) atomicMax(ag + 4 * r + 1, v1);
        if (v2 > c.z) atomicMax(ag + 4 * r + 2, v2);
        if (v3 > c.w) atomicMax(ag + 4 * r + 3, v3);
    }
}

// init agg=enc(0), g=enc(0), hist=0. Grid covers NN*H = 3.2M.
__global__ __launch_bounds__(256) void k_init(unsigned* __restrict__ agg,
                                              unsigned* __restrict__ g,
                                              unsigned* __restrict__ hist) {
    int i = blockIdx.x * 256 + threadIdx.x;
    agg[i] = 0x80000000u;
    if (i < NG * H) g[i] = 0x80000000u;
    if (i < NN) hist[i] = 0u;
}

// Pack transposed weight columns for streaming (uniform/scalar) access:
//   Wt[j][8]  = { b1a[j], W1a[0][j]..W1a[5][j], 0 }        (layer-1 t weights)
//   WpT[j][4] = { W2a[32][j], W2a[33][j], W2a[34][j], 0 }  (layer-2 dst-term)
__global__ __launch_bounds__(64) void k_packw(const float* __restrict__ W1a,
                                              const float* __restrict__ b1a,
                                              const float* __restrict__ W2a,
                                              float* __restrict__ Wt,
                                              float* __restrict__ WpT) {
    int j = threadIdx.x;
    if (j >= H) return;
    Wt[8 * j] = b1a[j];
#pragma unroll
    for (int i = 0; i < 6; i++) Wt[8 * j + 1 + i] = W1a[i * H + j];
    Wt[8 * j + 7] = 0.f;
#pragma unroll
    for (int i = 0; i < 3; i++) WpT[4 * j + i] = W2a[(32 + i) * H + j];
    WpT[4 * j + 3] = 0.f;
}

__global__ __launch_bounds__(256) void k_hist(const int* __restrict__ dst,
                                              unsigned* __restrict__ hist) {
    int e = blockIdx.x * 256 + threadIdx.x;   // grid covers exactly NE
    atomicAdd(&hist[dst[e]], 1u);
}

// Block-level exclusive scan (Hillis-Steele in LDS), 256 elems/block.
__global__ __launch_bounds__(256) void k_scan1(const unsigned* __restrict__ hist,
                                               unsigned* __restrict__ pre,
                                               unsigned* __restrict__ bsum) {
    __shared__ unsigned sd[256];
    int tid = threadIdx.x;
    int i = blockIdx.x * 256 + tid;
    unsigned v = (i < NN) ? hist[i] : 0u;
    sd[tid] = v;
    __syncthreads();
    for (int off = 1; off < 256; off <<= 1) {
        unsigned t = (tid >= off) ? sd[tid - off] : 0u;
        __syncthreads();
        sd[tid] += t;
        __syncthreads();
    }
    if (i < NN) pre[i] = sd[tid] - v;
    if (tid == 255) bsum[blockIdx.x] = sd[255];
}

__global__ __launch_bounds__(512) void k_scan2(const unsigned* __restrict__ bsum,
                                               unsigned* __restrict__ bpre) {
    __shared__ unsigned sd[512];
    int t = threadIdx.x;
    unsigned v = (t < SB) ? bsum[t] : 0u;
    sd[t] = v;
    __syncthreads();
    for (int off = 1; off < 512; off <<= 1) {
        unsigned x = (t >= off) ? sd[t - off] : 0u;
        __syncthreads();
        sd[t] += x;
        __syncthreads();
    }
    if (t < SB) bpre[t] = sd[t] - v;
}

// cursors[i] = global exclusive prefix (scatter cursor); ends[i] = prefix+count.
__global__ __launch_bounds__(256) void k_scan3(const unsigned* __restrict__ pre,
                                               const unsigned* __restrict__ bpre,
                                               const unsigned* __restrict__ hist,
                                               unsigned* __restrict__ cursors,
                                               unsigned* __restrict__ ends) {
    int i = blockIdx.x * 256 + threadIdx.x;
    if (i < NN) {
        unsigned o = pre[i] + bpre[blockIdx.x];
        cursors[i] = o;
        ends[i] = o + hist[i];
    }
}

// Scatter src ids into dst-sorted order (order within a run is nondeterministic
// but max-reduction is order-free).
__global__ __launch_bounds__(256) void k_scatter(const int* __restrict__ src,
                                                 const int* __restrict__ dst,
                                                 unsigned* __restrict__ cursors,
                                                 unsigned* __restrict__ srcS) {
    int e = blockIdx.x * 256 + threadIdx.x;   // grid covers exactly NE
    int d = dst[e];
    unsigned slot = atomicAdd(&cursors[d], 1u);
    srcS[slot] = (unsigned)src[e];
}

// chunk_node[c] = dst node owning edge c*CE = smallest n with ends[n] > c*CE.
__global__ __launch_bounds__(256) void k_chunks(const unsigned* __restrict__ ends,
                                                unsigned* __restrict__ chunk_node) {
    int c = blockIdx.x * 256 + threadIdx.x;
    if (c >= NCH) return;
    unsigned target = (unsigned)c * CE;
    int lo = 0, hi = NN - 1;
    while (lo < hi) {
        int mid = (lo + hi) >> 1;
        if (ends[mid] <= target) lo = mid + 1; else hi = mid;
    }
    chunk_node[c] = (unsigned)lo;
}

// Per-edge layer-1 message: m[k] += W1b[j][k] * relu(Wt_j . (1,ps,ps-pd)).
// j-loop rolled (tiny I$ body); weights are uniform-address -> scalar loads.
__device__ __forceinline__ void edge1_msg(float ps0, float ps1, float ps2,
                                          float pd0, float pd1, float pd2,
                                          const float* __restrict__ Wt,
                                          const float* __restrict__ W1b,
                                          float (&m)[H]) {
    float e0 = ps0 - pd0, e1 = ps1 - pd1, e2 = ps2 - pd2;
#pragma unroll 1
    for (int j = 0; j < H; j++) {
        const float* wr = Wt + (j << 3);
        float t = wr[0];
        t = fmaf(ps0, wr[1], t); t = fmaf(ps1, wr[2], t); t = fmaf(ps2, wr[3], t);
        t = fmaf(e0, wr[4], t);  t = fmaf(e1, wr[5], t);  t = fmaf(e2, wr[6], t);
        t = fmaxf(t, 0.f);
        const float* br = W1b + (j << 5);
#pragma unroll
        for (int k = 0; k < H; k++) m[k] = fmaf(t, br[k], m[k]);
    }
}

// Layer-1 edge kernel: 8 dst-sorted edges/thread; src pos prefetched one edge
// ahead (ping-pong psA/psB), so the srcS->pos chain hides under ~2500 cy of FMA.
__global__ __launch_bounds__(256) __attribute__((amdgpu_waves_per_eu(4)))
void k_edge1(const unsigned* __restrict__ srcS,
             const unsigned* __restrict__ ends,
             const unsigned* __restrict__ chunk_node,
             const float* __restrict__ pos,
             const float* __restrict__ Wt,
             const float* __restrict__ W1b,
             const float* __restrict__ b1b,
             unsigned* __restrict__ agg) {
    int gid = blockIdx.x * 256 + threadIdx.x;
    if (gid >= NCH) return;
    unsigned base = (unsigned)gid * CE;
    int cur = (int)chunk_node[gid];
    unsigned end_cur = ends[cur];
    float pd0 = pos[3 * cur], pd1 = pos[3 * cur + 1], pd2 = pos[3 * cur + 2];
    int sA = (int)srcS[base];
    float psA0 = pos[3 * sA], psA1 = pos[3 * sA + 1], psA2 = pos[3 * sA + 2];
    float macc[H];
#pragma unroll
    for (int k = 0; k < H; k++) macc[k] = 0.f;
#pragma unroll 1
    for (int c = 0; c < CE; c += 2) {
        // prefetch edge c+1's src pos (independent of edge c's compute)
        int sB = (int)srcS[base + c + 1];
        float psB0 = pos[3 * sB], psB1 = pos[3 * sB + 1], psB2 = pos[3 * sB + 2];
        // ---- edge c ----
        if (base + c >= end_cur) {
            flush_row(agg, cur, macc);
            do { cur++; end_cur = ends[cur]; } while (base + c >= end_cur);
            pd0 = pos[3 * cur]; pd1 = pos[3 * cur + 1]; pd2 = pos[3 * cur + 2];
#pragma unroll
            for (int k = 0; k < H; k++) macc[k] = 0.f;
        }
        {
            float m[H];
#pragma unroll
            for (int k = 0; k < H; k++) m[k] = b1b[k];
            edge1_msg(psA0, psA1, psA2, pd0, pd1, pd2, Wt, W1b, m);
#pragma unroll
            for (int k = 0; k < H; k++) macc[k] = fmaxf(macc[k], m[k]);
        }
        // prefetch edge c+2's src pos
        if (c + 2 < CE) {
            int sA2 = (int)srcS[base + c + 2];
            psA0 = pos[3 * sA2]; psA1 = pos[3 * sA2 + 1]; psA2 = pos[3 * sA2 + 2];
        }
        // ---- edge c+1 ----
        if (base + c + 1 >= end_cur) {
            flush_row(agg, cur, macc);
            do { cur++; end_cur = ends[cur]; } while (base + c + 1 >= end_cur);
            pd0 = pos[3 * cur]; pd1 = pos[3 * cur + 1]; pd2 = pos[3 * cur + 2];
#pragma unroll
            for (int k = 0; k < H; k++) macc[k] = 0.f;
        }
        {
            float m[H];
#pragma unroll
            for (int k = 0; k < H; k++) m[k] = b1b[k];
            edge1_msg(psB0, psB1, psB2, pd0, pd1, pd2, Wt, W1b, m);
#pragma unroll
            for (int k = 0; k < H; k++) macc[k] = fmaxf(macc[k], m[k]);
        }
    }
    flush_row(agg, cur, macc);
}

// Layer-2 node precompute: E2[n] = b2a + h[n]@W2a[0:32] + pos[n]@W2a[32:35];
// also resets agg row for reuse by layer 2 (each thread owns its row).
__global__ __launch_bounds__(256) void k_pre2(const float* __restrict__ pos,
                                              unsigned* __restrict__ agg,
                                              const float* __restrict__ W2a,
                                              const float* __restrict__ b2a,
                                              float* __restrict__ E2) {
    int n = blockIdx.x * 256 + threadIdx.x;
    if (n >= NN) return;
    float h[H];
    uint4* A4 = (uint4*)(agg + (size_t)n * H);
#pragma unroll
    for (int r = 0; r < 8; r++) {
        uint4 u = A4[r];
        h[4 * r + 0] = decf(u.x);
        h[4 * r + 1] = decf(u.y);
        h[4 * r + 2] = decf(u.z);
        h[4 * r + 3] = decf(u.w);
        A4[r] = make_uint4(0x80000000u, 0x80000000u, 0x80000000u, 0x80000000u);
    }
    float p0 = pos[3 * n], p1 = pos[3 * n + 1], p2 = pos[3 * n + 2];
    float ev[H];
#pragma unroll
    for (int k = 0; k < H; k++) {
        float v = b2a[k];
        v = fmaf(p0, W2a[32 * H + k], v);
        v = fmaf(p1, W2a[33 * H + k], v);
        v = fmaf(p2, W2a[34 * H + k], v);
        ev[k] = v;
    }
#pragma unroll
    for (int j = 0; j < H; j++) {
        float hj = h[j];
#pragma unroll
        for (int k = 0; k < H; k++) ev[k] = fmaf(hj, W2a[j * H + k], ev[k]);
    }
    float4* E4 = (float4*)(E2 + (size_t)n * H);
#pragma unroll
    for (int r = 0; r < 8; r++)
        E4[r] = make_float4(ev[4 * r], ev[4 * r + 1], ev[4 * r + 2], ev[4 * r + 3]);
}

// Per-edge layer-2 message from a register-held E2 row (static indexing only).
__device__ __forceinline__ void edge2_msg(const float4 (&r)[8],
                                          float pd0, float pd1, float pd2,
                                          const float* __restrict__ WpT,
                                          const float* __restrict__ W2b,
                                          float (&m)[H]) {
#pragma unroll
    for (int cc = 0; cc < 8; cc++) {
        float ej4[4] = {r[cc].x, r[cc].y, r[cc].z, r[cc].w};
#pragma unroll
        for (int q = 0; q < 4; q++) {
            int j = 4 * cc + q;
            const float* wp = WpT + 4 * j;
            float w = fmaf(pd0, wp[0], fmaf(pd1, wp[1], pd2 * wp[2]));
            float t = fmaxf(ej4[q] - w, 0.f);
            const float* br = W2b + (j << 5);
#pragma unroll
            for (int k = 0; k < H; k++) m[k] = fmaf(t, br[k], m[k]);
        }
    }
}

// Layer-2 edge kernel: full E2 row (8 x float4) prefetched ONE EDGE AHEAD
// (ping-pong ra/rb, c-loop rolled at step 2 so all reg indexing is static).
// The ~2300 cy of FMA per edge hides the ~500 cy random-row gather entirely.
__global__ __launch_bounds__(256) __attribute__((amdgpu_waves_per_eu(3)))
void k_edge2(const unsigned* __restrict__ srcS,
             const unsigned* __restrict__ ends,
             const unsigned* __restrict__ chunk_node,
             const float* __restrict__ pos,
             const float* __restrict__ E2,
             const float* __restrict__ WpT,
             const float* __restrict__ W2b,
             const float* __restrict__ b2b,
             unsigned* __restrict__ agg) {
    int gid = blockIdx.x * 256 + threadIdx.x;
    if (gid >= NCH) return;
    unsigned base = (unsigned)gid * CE;
    int cur = (int)chunk_node[gid];
    unsigned end_cur = ends[cur];
    float pd0 = pos[3 * cur], pd1 = pos[3 * cur + 1], pd2 = pos[3 * cur + 2];
    float4 ra[8], rb[8];
    {
        int s0 = (int)srcS[base];
        const float4* er = (const float4*)(E2 + (size_t)s0 * H);
#pragma unroll
        for (int i = 0; i < 8; i++) ra[i] = er[i];
    }
    float macc[H];
#pragma unroll
    for (int k = 0; k < H; k++) macc[k] = 0.f;
#pragma unroll 1
    for (int c = 0; c < CE; c += 2) {
        // issue edge c+1's row while edge c computes
        {
            int sB = (int)srcS[base + c + 1];
            const float4* er = (const float4*)(E2 + (size_t)sB * H);
#pragma unroll
            for (int i = 0; i < 8; i++) rb[i] = er[i];
        }
        // ---- edge c (row in ra) ----
        if (base + c >= end_cur) {
            flush_row(agg, cur, macc);
            do { cur++; end_cur = ends[cur]; } while (base + c >= end_cur);
            pd0 = pos[3 * cur]; pd1 = pos[3 * cur + 1]; pd2 = pos[3 * cur + 2];
#pragma unroll
            for (int k = 0; k < H; k++) macc[k] = 0.f;
        }
        {
            float m[H];
#pragma unroll
            for (int k = 0; k < H; k++) m[k] = b2b[k];
            edge2_msg(ra, pd0, pd1, pd2, WpT, W2b, m);
#pragma unroll
            for (int k = 0; k < H; k++) macc[k] = fmaxf(macc[k], m[k]);
        }
        // issue edge c+2's row while edge c+1 computes
        if (c + 2 < CE) {
            int sA = (int)srcS[base + c + 2];
            const float4* er = (const float4*)(E2 + (size_t)sA * H);
#pragma unroll
            for (int i = 0; i < 8; i++) ra[i] = er[i];
        }
        // ---- edge c+1 (row in rb) ----
        if (base + c + 1 >= end_cur) {
            flush_row(agg, cur, macc);
            do { cur++; end_cur = ends[cur]; } while (base + c + 1 >= end_cur);
            pd0 = pos[3 * cur]; pd1 = pos[3 * cur + 1]; pd2 = pos[3 * cur + 2];
#pragma unroll
            for (int k = 0; k < H; k++) macc[k] = 0.f;
        }
        {
            float m[H];
#pragma unroll
            for (int k = 0; k < H; k++) m[k] = b2b[k];
            edge2_msg(rb, pd0, pd1, pd2, WpT, W2b, m);
#pragma unroll
            for (int k = 0; k < H; k++) macc[k] = fmaxf(macc[k], m[k]);
        }
    }
    flush_row(agg, cur, macc);
}

// Graph max-pool (encoded domain; max commutes with monotone encoding).
__global__ __launch_bounds__(256) void k_pool(const unsigned* __restrict__ agg,
                                              const int* __restrict__ batch,
                                              unsigned* __restrict__ g) {
    int n = blockIdx.x * 256 + threadIdx.x;
    if (n >= NN) return;
    int bidx = batch[n];
    unsigned* gb = g + (size_t)bidx * H;
    const uint4* A4 = (const uint4*)(agg + (size_t)n * H);
#pragma unroll
    for (int r = 0; r < 8; r++) {
        uint4 v = A4[r];
        uint4 c = ((const uint4*)gb)[r];
        if (v.x > c.x) atomicMax(gb + 4 * r + 0, v.x);
        if (v.y > c.y) atomicMax(gb + 4 * r + 1, v.y);
        if (v.z > c.z) atomicMax(gb + 4 * r + 2, v.z);
        if (v.w > c.w) atomicMax(gb + 4 * r + 3, v.w);
    }
}

__global__ __launch_bounds__(256) void k_out(const unsigned* __restrict__ g,
                                             const float* __restrict__ Wout,
                                             const float* __restrict__ bout,
                                             float* __restrict__ out) {
    int bidx = threadIdx.x;  // one block of 256
    float acc = bout[0];
#pragma unroll
    for (int k = 0; k < H; k++) acc = fmaf(decf(g[bidx * H + k]), Wout[k], acc);
    out[bidx] = acc;
}

extern "C" void kernel_launch(void* const* d_in, const int* in_sizes, int n_in,
                              void* d_out, int out_size, void* d_ws, size_t ws_size,
                              hipStream_t stream) {
    const float* pos  = (const float*)d_in[0];
    const int* src    = (const int*)d_in[1];
    const int* dst    = src + NE;
    const int* batch  = (const int*)d_in[2];
    const float* W1a  = (const float*)d_in[3];
    const float* b1a  = (const float*)d_in[4];
    const float* W1b  = (const float*)d_in[5];
    const float* b1b  = (const float*)d_in[6];
    const float* W2a  = (const float*)d_in[7];
    const float* b2a  = (const float*)d_in[8];
    const float* W2b  = (const float*)d_in[9];
    const float* b2b  = (const float*)d_in[10];
    const float* Wout = (const float*)d_in[11];
    const float* bout = (const float*)d_in[12];
    float* out = (float*)d_out;

    const size_t SZ = (size_t)NN * H;  // 3.2M words
    unsigned* agg        = (unsigned*)d_ws;          // 12.8 MB
    float*    E2         = (float*)d_ws + SZ;        // 12.8 MB (aliased pre-edge1)
    unsigned* srcS       = (unsigned*)d_ws + 2 * SZ; // 12.8 MB (dst-sorted src ids)
    unsigned* g          = (unsigned*)d_ws + 3 * SZ; // 32 KB
    unsigned* ends       = g + NG * H;               // 400 KB (CSR run ends)
    unsigned* chunk_node = ends + NN;                // 1.6 MB (first dst per chunk)
    unsigned* bsum       = chunk_node + NCH;         // scan partials
    unsigned* bpre       = bsum + SB + 1;
    float*    Wt         = (float*)(bpre + SB + 1);  // 256 floats packed t-weights
    float*    WpT        = Wt + 8 * H;               // 128 floats packed dst-term
    // Sort-phase temporaries aliased into E2's space (dead before k_pre2 writes):
    unsigned* hist    = (unsigned*)E2;
    unsigned* pre     = hist + NN;
    unsigned* cursors = pre + NN;

    const int EDGE_BLOCKS  = NE / 256;          // 12500
    const int INIT_BLOCKS  = (NN * H) / 256;    // 12500
    const int NODE_BLOCKS  = SB;                // 391
    const int CHUNK_BLOCKS = (NCH + 255) / 256; // 1563

    k_init<<<INIT_BLOCKS, 256, 0, stream>>>(agg, g, hist);
    k_packw<<<1, 64, 0, stream>>>(W1a, b1a, W2a, Wt, WpT);
    k_hist<<<EDGE_BLOCKS, 256, 0, stream>>>(dst, hist);
    k_scan1<<<NODE_BLOCKS, 256, 0, stream>>>(hist, pre, bsum);
    k_scan2<<<1, 512, 0, stream>>>(bsum, bpre);
    k_scan3<<<NODE_BLOCKS, 256, 0, stream>>>(pre, bpre, hist, cursors, ends);
    k_scatter<<<EDGE_BLOCKS, 256, 0, stream>>>(src, dst, cursors, srcS);
    k_chunks<<<CHUNK_BLOCKS, 256, 0, stream>>>(ends, chunk_node);
    k_edge1<<<CHUNK_BLOCKS, 256, 0, stream>>>(srcS, ends, chunk_node, pos,
                                              Wt, W1b, b1b, agg);
    k_pre2<<<NODE_BLOCKS, 256, 0, stream>>>(pos, agg, W2a, b2a, E2);
    k_edge2<<<CHUNK_BLOCKS, 256, 0, stream>>>(srcS, ends, chunk_node, pos, E2,
                                              WpT, W2b, b2b, agg);
    k_pool<<<NODE_BLOCKS, 256, 0, stream>>>(agg, batch, g);
    k_out<<<1, 256, 0, stream>>>(g, Wout, bout, out);
}